// Round 3
// baseline (15452.240 us; speedup 1.0000x reference)
//
#include <hip/hip_runtime.h>
#include <hip/hip_bf16.h>
#include <math.h>

// LinearTransformerAgent: B=64 T=512 D=512 H=8 DH=64 L=4 DFF=2048
// Round 3 (= R2 resubmit; R2 bench was a broker timeout, kernel never ran).
// Correct f32 implementation with FRUGAL workspace (<=134.5 MB).
//   R1 post-mortem: core dump — most likely d_ws overflow (needed 384 MB,
//   never checked ws_size). This round: row-chunked dataflow, LN fused into
//   GEMM A-staging, attn output written in place over dead q-slice.
// ws layout: x[ROWS*D] (64MB) | buf[CH_ROWS*DFF] (64MB) | stats[ROWS*2] (256KB)

#define B_    64
#define T_    512
#define DOBS  64
#define D_    512
#define H_    8
#define DH_   64
#define L_    4
#define NACT  16
#define DFF   2048
#define ROWS  (B_ * T_)          // 32768
#define RC_   4                  // row chunks
#define CH_ROWS (ROWS / RC_)     // 8192 rows = 16 batches
#define CH_B  (B_ / RC_)         // 16 batches per chunk

__device__ __forceinline__ float gelu_tanh(float v) {
    float u = 0.7978845608028654f * (v + 0.044715f * v * v * v);
    return 0.5f * v * (1.0f + tanhf(u));
}

__device__ __forceinline__ float wave_sum(float v) {
#pragma unroll
    for (int o = 32; o > 0; o >>= 1) v += __shfl_down(v, o);
    return v;
}

// ---------------------------------------------------------------- embed
__global__ __launch_bounds__(256) void embed_kernel(
    const float* __restrict__ obs, const int* __restrict__ act,
    const float* __restrict__ rew, const int* __restrict__ sobs,
    const float* __restrict__ W_obs, const float* __restrict__ b_obs,
    const float* __restrict__ E_act, const float* __restrict__ W_rew,
    const float* __restrict__ b_rew, const float* __restrict__ E_time,
    float* __restrict__ x) {
    const int row = blockIdx.x;            // b*T + t
    const int b = row >> 9, t = row & 511;
    const int tid = threadIdx.x;
    __shared__ float o[DOBS];
    if (tid < DOBS) o[tid] = obs[(size_t)row * DOBS + tid];
    __syncthreads();
    const int a = act[row];
    const float r = rew[row];
    const int ti = sobs[b] + t;
#pragma unroll
    for (int dq = 0; dq < 2; ++dq) {
        const int d = tid + dq * 256;
        float acc = b_obs[d] + b_rew[d] + E_act[(size_t)a * D_ + d]
                  + r * W_rew[d] + E_time[(size_t)ti * D_ + d];
#pragma unroll 8
        for (int k = 0; k < DOBS; ++k) acc = fmaf(o[k], W_obs[(size_t)k * D_ + d], acc);
        x[(size_t)row * D_ + d] = acc;
    }
}

// ---------------------------------------------------------------- row stats
// one wave per row: mean & rstd of x[row][0:512] -> stats[row*2 +{0,1}]
__global__ __launch_bounds__(256) void rowstat_kernel(
    const float* __restrict__ x, float* __restrict__ stats) {
    const int w = threadIdx.x >> 6, lane = threadIdx.x & 63;
    const int row = blockIdx.x * 4 + w;
    const float4* p = (const float4*)(x + (size_t)row * D_);
    float4 a = p[lane], b = p[lane + 64];
    float s = a.x + a.y + a.z + a.w + b.x + b.y + b.z + b.w;
    float q = a.x*a.x + a.y*a.y + a.z*a.z + a.w*a.w
            + b.x*b.x + b.y*b.y + b.z*b.z + b.w*b.w;
    s = wave_sum(s);
    q = wave_sum(q);
    if (lane == 0) {
        const float mean = s * (1.0f / 512.0f);
        const float var = q * (1.0f / 512.0f) - mean * mean;
        stats[(size_t)row * 2 + 0] = mean;
        stats[(size_t)row * 2 + 1] = rsqrtf(var + 1e-6f);
    }
}

// ---------------------------------------------------------------- GEMM
// C[M,N](ldc) = op( LN?(A[M,K](lda)) @ W[K,N] + bias )   (+C if RES, gelu if GELU)
// LN applied during A-staging: (a - mean[row]) * rstd[row] * ln_s[k] + ln_b[k]
template <bool LN, bool GELU, bool RES>
__global__ __launch_bounds__(256) void gemm128(
    const float* __restrict__ A, int lda,
    const float* __restrict__ W,
    const float* __restrict__ bias,
    const float* __restrict__ stats,
    const float* __restrict__ ln_s, const float* __restrict__ ln_b,
    float* __restrict__ C, int ldc,
    int M, int N, int K) {
    __shared__ float As[8][132];
    __shared__ float Bs[8][132];
    const int tid = threadIdx.x;
    const int tx = tid & 15, ty = tid >> 4;
    const int row0 = blockIdx.y * 128, col0 = blockIdx.x * 128;

    float acc[8][8];
#pragma unroll
    for (int i = 0; i < 8; ++i)
#pragma unroll
        for (int j = 0; j < 8; ++j) acc[i][j] = 0.0f;

    const int ar = tid >> 1, ak = (tid & 1) * 4;   // A: 128 rows x 8 k
    const int bc = (tid & 31) * 4, bk = tid >> 5;  // B: 8 k x 128 cols
    const float* Ap = A + (size_t)(row0 + ar) * lda + ak;
    const float* Wp = W + (size_t)bk * N + col0 + bc;
    float mean = 0.0f, rstd = 1.0f;
    if (LN) {
        mean = stats[(size_t)(row0 + ar) * 2 + 0];
        rstd = stats[(size_t)(row0 + ar) * 2 + 1];
    }

    for (int k0 = 0; k0 < K; k0 += 8) {
        float4 av = *(const float4*)(Ap + k0);
        if (LN) {
            float4 s4 = *(const float4*)(ln_s + k0 + ak);
            float4 b4 = *(const float4*)(ln_b + k0 + ak);
            av.x = (av.x - mean) * rstd * s4.x + b4.x;
            av.y = (av.y - mean) * rstd * s4.y + b4.y;
            av.z = (av.z - mean) * rstd * s4.z + b4.z;
            av.w = (av.w - mean) * rstd * s4.w + b4.w;
        }
        float4 bv = *(const float4*)(Wp + (size_t)k0 * N);
        As[ak + 0][ar] = av.x;
        As[ak + 1][ar] = av.y;
        As[ak + 2][ar] = av.z;
        As[ak + 3][ar] = av.w;
        *(float4*)&Bs[bk][bc] = bv;
        __syncthreads();
#pragma unroll
        for (int kk = 0; kk < 8; ++kk) {
            float4 a0 = *(const float4*)&As[kk][ty * 8];
            float4 a1 = *(const float4*)&As[kk][ty * 8 + 4];
            float4 b0 = *(const float4*)&Bs[kk][tx * 8];
            float4 b1 = *(const float4*)&Bs[kk][tx * 8 + 4];
            float a[8] = {a0.x, a0.y, a0.z, a0.w, a1.x, a1.y, a1.z, a1.w};
            float bb[8] = {b0.x, b0.y, b0.z, b0.w, b1.x, b1.y, b1.z, b1.w};
#pragma unroll
            for (int i = 0; i < 8; ++i)
#pragma unroll
                for (int j = 0; j < 8; ++j) acc[i][j] = fmaf(a[i], bb[j], acc[i][j]);
        }
        __syncthreads();
    }

    float bcol[8];
#pragma unroll
    for (int j = 0; j < 8; ++j) bcol[j] = bias[col0 + tx * 8 + j];
#pragma unroll
    for (int i = 0; i < 8; ++i) {
        float* Cp = C + (size_t)(row0 + ty * 8 + i) * ldc + col0 + tx * 8;
#pragma unroll
        for (int j4 = 0; j4 < 2; ++j4) {
            float4 v;
            v.x = acc[i][j4 * 4 + 0] + bcol[j4 * 4 + 0];
            v.y = acc[i][j4 * 4 + 1] + bcol[j4 * 4 + 1];
            v.z = acc[i][j4 * 4 + 2] + bcol[j4 * 4 + 2];
            v.w = acc[i][j4 * 4 + 3] + bcol[j4 * 4 + 3];
            if (GELU) {
                v.x = gelu_tanh(v.x); v.y = gelu_tanh(v.y);
                v.z = gelu_tanh(v.z); v.w = gelu_tanh(v.w);
            }
            if (RES) {
                float4 o = *(const float4*)(Cp + j4 * 4);
                v.x += o.x; v.y += o.y; v.z += o.z; v.w += o.w;
            }
            *(float4*)(Cp + j4 * 4) = v;
        }
    }
}

// ---------------------------------------------------------------- attention
// per (b,h) in a chunk of CH_B batches: stream 8 tiles of 64:
//   out = tril(QK^T)V + Q S_run; S_run += K^T V
// attn out is written IN PLACE over the (dead) q-slice of the qkv buffer.
__global__ __launch_bounds__(256) void attn_kernel(
    float* __restrict__ qkv, const float* __restrict__ state_in,
    float* __restrict__ state_out, int layer, int b0) {
    __shared__ float Qs[64][64];
    __shared__ float KsT[64][64];  // K transposed: KsT[d][t]
    __shared__ float Vs[64][64];
    __shared__ float Ss[64][64];
    const int bh = blockIdx.x, bl = bh >> 3, h = bh & 7;
    const int b = b0 + bl;
    const int tid = threadIdx.x, tx = tid & 15, ty = tid >> 4;
    const int r0 = ty * 4, c0 = tx * 4;
    const size_t soff = (((size_t)b * L_ + layer) * H_ + h) * (DH_ * DH_);

    for (int i = tid; i < 4096; i += 256) Ss[i >> 6][i & 63] = state_in[soff + i];
    __syncthreads();

    for (int tile = 0; tile < 8; ++tile) {
        const int t0 = tile * 64;
        for (int idx = tid; idx < 1024; idx += 256) {
            const int r = idx >> 4, c = (idx & 15) * 4;
            const float* base = qkv + ((size_t)(bl * T_ + t0 + r)) * (3 * D_) + h * DH_;
            *(float4*)&Qs[r][c] = *(const float4*)(base + c);
            *(float4*)&Vs[r][c] = *(const float4*)(base + 2 * D_ + c);
            const int t = idx & 63, d = (idx >> 6) * 4;
            const float* kb = qkv + ((size_t)(bl * T_ + t0 + t)) * (3 * D_) + h * DH_ + D_ + d;
            float4 k4 = *(const float4*)kb;
            KsT[d + 0][t] = k4.x; KsT[d + 1][t] = k4.y;
            KsT[d + 2][t] = k4.z; KsT[d + 3][t] = k4.w;
        }
        __syncthreads();

        // out = Q @ S_run
        float oacc[4][4];
#pragma unroll
        for (int i = 0; i < 4; ++i)
#pragma unroll
            for (int j = 0; j < 4; ++j) oacc[i][j] = 0.0f;
#pragma unroll 4
        for (int kk = 0; kk < 64; ++kk) {
            float a[4], s[4];
#pragma unroll
            for (int i = 0; i < 4; ++i) a[i] = Qs[r0 + i][kk];
#pragma unroll
            for (int j = 0; j < 4; ++j) s[j] = Ss[kk][c0 + j];
#pragma unroll
            for (int i = 0; i < 4; ++i)
#pragma unroll
                for (int j = 0; j < 4; ++j) oacc[i][j] = fmaf(a[i], s[j], oacc[i][j]);
        }

        // A = QK^T (masked) -> staged into Qs after all Q reads complete
        float aacc[4][4];
#pragma unroll
        for (int i = 0; i < 4; ++i)
#pragma unroll
            for (int j = 0; j < 4; ++j) aacc[i][j] = 0.0f;
#pragma unroll 4
        for (int kk = 0; kk < 64; ++kk) {
            float a[4], k[4];
#pragma unroll
            for (int i = 0; i < 4; ++i) a[i] = Qs[r0 + i][kk];
#pragma unroll
            for (int j = 0; j < 4; ++j) k[j] = KsT[kk][c0 + j];
#pragma unroll
            for (int i = 0; i < 4; ++i)
#pragma unroll
                for (int j = 0; j < 4; ++j) aacc[i][j] = fmaf(a[i], k[j], aacc[i][j]);
        }
        __syncthreads();
#pragma unroll
        for (int i = 0; i < 4; ++i)
#pragma unroll
            for (int j = 0; j < 4; ++j)
                Qs[r0 + i][c0 + j] = (c0 + j <= r0 + i) ? aacc[i][j] : 0.0f;
        __syncthreads();

        // out += A @ V
#pragma unroll 4
        for (int kk = 0; kk < 64; ++kk) {
            float a[4], v[4];
#pragma unroll
            for (int i = 0; i < 4; ++i) a[i] = Qs[r0 + i][kk];
#pragma unroll
            for (int j = 0; j < 4; ++j) v[j] = Vs[kk][c0 + j];
#pragma unroll
            for (int i = 0; i < 4; ++i)
#pragma unroll
                for (int j = 0; j < 4; ++j) oacc[i][j] = fmaf(a[i], v[j], oacc[i][j]);
        }
        // write out over dead q-slice (head-exclusive columns)
#pragma unroll
        for (int i = 0; i < 4; ++i) {
            float4 v = {oacc[i][0], oacc[i][1], oacc[i][2], oacc[i][3]};
            *(float4*)(qkv + ((size_t)(bl * T_ + t0 + r0 + i)) * (3 * D_) + h * DH_ + c0) = v;
        }

        // S_run += K^T V
        float sacc[4][4];
#pragma unroll
        for (int i = 0; i < 4; ++i)
#pragma unroll
            for (int j = 0; j < 4; ++j) sacc[i][j] = 0.0f;
#pragma unroll 4
        for (int kk = 0; kk < 64; ++kk) {
            float k[4], v[4];
#pragma unroll
            for (int i = 0; i < 4; ++i) k[i] = KsT[r0 + i][kk];
#pragma unroll
            for (int j = 0; j < 4; ++j) v[j] = Vs[kk][c0 + j];
#pragma unroll
            for (int i = 0; i < 4; ++i)
#pragma unroll
                for (int j = 0; j < 4; ++j) sacc[i][j] = fmaf(k[i], v[j], sacc[i][j]);
        }
#pragma unroll
        for (int i = 0; i < 4; ++i)
#pragma unroll
            for (int j = 0; j < 4; ++j) Ss[r0 + i][c0 + j] += sacc[i][j];
        __syncthreads();
    }

    for (int i = tid; i < 4096; i += 256) state_out[soff + i] = Ss[i >> 6][i & 63];
}

// ---------------------------------------------------------------- final LN + heads
__global__ __launch_bounds__(256) void head_kernel(
    const float* __restrict__ x, const float* __restrict__ lnf_s,
    const float* __restrict__ lnf_b, const float* __restrict__ W_actor,
    const float* __restrict__ b_actor, const float* __restrict__ W_critic,
    const float* __restrict__ b_critic, float* __restrict__ logits,
    float* __restrict__ val) {
    __shared__ float n[D_];
    __shared__ float red[8];
    const int row = blockIdx.x, tid = threadIdx.x;
    const int lane = tid & 63, w = tid >> 6;
    float2 v = ((const float2*)(x + (size_t)row * D_))[tid];
    float p = wave_sum(v.x + v.y);
    if (lane == 0) red[w] = p;
    __syncthreads();
    const float mean = (red[0] + red[1] + red[2] + red[3]) * (1.0f / 512.0f);
    const float d0 = v.x - mean, d1 = v.y - mean;
    float q = wave_sum(d0 * d0 + d1 * d1);
    if (lane == 0) red[4 + w] = q;
    __syncthreads();
    const float var = (red[4] + red[5] + red[6] + red[7]) * (1.0f / 512.0f);
    const float rinv = rsqrtf(var + 1e-6f);
    float2 sc = ((const float2*)lnf_s)[tid];
    float2 bi = ((const float2*)lnf_b)[tid];
    n[2 * tid + 0] = d0 * rinv * sc.x + bi.x;
    n[2 * tid + 1] = d1 * rinv * sc.y + bi.y;
    __syncthreads();
#pragma unroll
    for (int jj = 0; jj < 4; ++jj) {
        const int j = w * 4 + jj;
        float pp = 0.0f;
#pragma unroll
        for (int d = lane; d < D_; d += 64) pp = fmaf(n[d], W_actor[d * NACT + j], pp);
        pp = wave_sum(pp);
        if (lane == 0) logits[(size_t)row * NACT + j] = pp + b_actor[j];
    }
    if (w == 0) {
        float pp = 0.0f;
#pragma unroll
        for (int d = lane; d < D_; d += 64) pp = fmaf(n[d], W_critic[d], pp);
        pp = wave_sum(pp);
        if (lane == 0) val[row] = pp + b_critic[0];
    }
}

__global__ void sobs_kernel(const int* __restrict__ sobs, float* __restrict__ out) {
    const int i = threadIdx.x;
    if (i < B_) out[i] = (float)(sobs[i] + T_);
}

// ---------------------------------------------------------------- launch
extern "C" void kernel_launch(void* const* d_in, const int* in_sizes, int n_in,
                              void* d_out, int out_size, void* d_ws, size_t ws_size,
                              hipStream_t stream) {
    const float* obs     = (const float*)d_in[0];
    const int*   act_p   = (const int*)d_in[1];
    const float* rew_p   = (const float*)d_in[2];
    const int*   sobs    = (const int*)d_in[3];
    const float* sblk    = (const float*)d_in[4];
    const float* W_obs   = (const float*)d_in[5];
    const float* b_obs   = (const float*)d_in[6];
    const float* E_act   = (const float*)d_in[7];
    const float* W_rew   = (const float*)d_in[8];
    const float* b_rew   = (const float*)d_in[9];
    const float* E_time  = (const float*)d_in[10];
    const float* ln1_s   = (const float*)d_in[11];
    const float* ln1_b   = (const float*)d_in[12];
    const float* Wqkv    = (const float*)d_in[13];
    const float* bqkv    = (const float*)d_in[14];
    const float* Wout    = (const float*)d_in[15];
    const float* bout    = (const float*)d_in[16];
    const float* ln2_s   = (const float*)d_in[17];
    const float* ln2_b   = (const float*)d_in[18];
    const float* W1      = (const float*)d_in[19];
    const float* b1      = (const float*)d_in[20];
    const float* W2      = (const float*)d_in[21];
    const float* b2      = (const float*)d_in[22];
    const float* lnf_s   = (const float*)d_in[23];
    const float* lnf_b   = (const float*)d_in[24];
    const float* W_actor = (const float*)d_in[25];
    const float* b_actor = (const float*)d_in[26];
    const float* W_crit  = (const float*)d_in[27];
    const float* b_crit  = (const float*)d_in[28];

    float* out        = (float*)d_out;
    float* out_blocks = out;                                   // B*L*H*DH*DH
    float* out_sobs   = out + (size_t)B_ * L_ * H_ * DH_ * DH_;
    float* out_logits = out_sobs + B_;
    float* out_val    = out_logits + (size_t)ROWS * NACT;

    // ws: x (64MB) | buf (64MB: qkv 8192x1536 or ff 8192x2048) | stats (256KB)
    float* x     = (float*)d_ws;
    float* buf   = x + (size_t)ROWS * D_;
    float* stats = buf + (size_t)CH_ROWS * DFF;
    const size_t need = ((size_t)ROWS * D_ + (size_t)CH_ROWS * DFF
                         + (size_t)ROWS * 2) * sizeof(float);
    if (ws_size < need) return;  // fail soft (absmax) instead of faulting

    embed_kernel<<<ROWS, 256, 0, stream>>>(obs, act_p, rew_p, sobs, W_obs, b_obs,
                                           E_act, W_rew, b_rew, E_time, x);
    for (int l = 0; l < L_; ++l) {
        rowstat_kernel<<<ROWS / 4, 256, 0, stream>>>(x, stats);
        for (int rc = 0; rc < RC_; ++rc) {
            const size_t ro = (size_t)rc * CH_ROWS;
            gemm128<true, false, false><<<dim3(12, CH_ROWS / 128), 256, 0, stream>>>(
                x + ro * D_, D_, Wqkv + (size_t)l * D_ * 3 * D_, bqkv + l * 3 * D_,
                stats + ro * 2, ln1_s + l * D_, ln1_b + l * D_,
                buf, 3 * D_, CH_ROWS, 3 * D_, D_);
            attn_kernel<<<CH_B * H_, 256, 0, stream>>>(buf, sblk, out_blocks, l, rc * CH_B);
            gemm128<false, false, true><<<dim3(4, CH_ROWS / 128), 256, 0, stream>>>(
                buf, 3 * D_, Wout + (size_t)l * D_ * D_, bout + l * D_,
                nullptr, nullptr, nullptr,
                x + ro * D_, D_, CH_ROWS, D_, D_);
        }
        rowstat_kernel<<<ROWS / 4, 256, 0, stream>>>(x, stats);
        for (int rc = 0; rc < RC_; ++rc) {
            const size_t ro = (size_t)rc * CH_ROWS;
            gemm128<true, true, false><<<dim3(16, CH_ROWS / 128), 256, 0, stream>>>(
                x + ro * D_, D_, W1 + (size_t)l * D_ * DFF, b1 + l * DFF,
                stats + ro * 2, ln2_s + l * D_, ln2_b + l * D_,
                buf, DFF, CH_ROWS, DFF, D_);
            gemm128<false, false, true><<<dim3(4, CH_ROWS / 128), 256, 0, stream>>>(
                buf, DFF, W2 + (size_t)l * DFF * D_, b2 + l * D_,
                nullptr, nullptr, nullptr,
                x + ro * D_, D_, CH_ROWS, D_, DFF);
        }
    }
    head_kernel<<<ROWS, 256, 0, stream>>>(x, lnf_s, lnf_b, W_actor, b_actor,
                                          W_crit, b_crit, out_logits, out_val);
    sobs_kernel<<<1, 64, 0, stream>>>(sobs, out_sobs);
}

// Round 4
// 2903.077 us; speedup vs baseline: 5.3227x; 5.3227x over previous
//
#include <hip/hip_runtime.h>
#include <hip/hip_bf16.h>
#include <math.h>

// LinearTransformerAgent R4: bf16 MFMA everywhere.
// B=64 T=512 D=512 H=8 DH=64 L=4 DFF=2048, ROWS=32768, row-chunks of 8192.
// ws (128 MiB exactly): x f32 64MB | h bf16 8MB | big bf16 32MB | Wt bf16 24MB

#define B_    64
#define T_    512
#define D_    512
#define H_    8
#define L_    4
#define NACT  16
#define DFF   2048
#define ROWS  (B_ * T_)
#define RC_   4
#define CH_ROWS (ROWS / RC_)     // 8192
#define CH_B  (B_ / RC_)         // 16

typedef __attribute__((ext_vector_type(8))) short short8;
typedef __attribute__((ext_vector_type(4))) float f32x4;
#define MFMA16(a, b, c) __builtin_amdgcn_mfma_f32_16x16x32_bf16(a, b, c, 0, 0, 0)

__device__ __forceinline__ ushort f2bf(float f) {
    union { float f; unsigned u; } c; c.f = f;
    unsigned r = c.u + 0x7FFF + ((c.u >> 16) & 1);
    return (ushort)(r >> 16);
}
__device__ __forceinline__ float gelu_tanh(float v) {
    float u = 0.7978845608028654f * (v + 0.044715f * v * v * v);
    return 0.5f * v * (1.0f + tanhf(u));
}
__device__ __forceinline__ float wave_sum(float v) {
#pragma unroll
    for (int o = 32; o > 0; o >>= 1) v += __shfl_xor(v, o);
    return v;
}
// XOR-swizzled byte offset into a [rows][128B] LDS tile (T2: 2-way residual)
__device__ __forceinline__ int sw(int row, int kb) {
    return row * 128 + (kb ^ ((row & 7) << 4));
}

// ---------------------------------------------------------------- weight transpose f32 -> bf16T
__global__ __launch_bounds__(256) void wtrans(
    const float* __restrict__ W, ushort* __restrict__ Wt, int K, int N) {
    __shared__ float tb[32][33];
    const int tid = threadIdx.x, tx = tid & 31, ty = tid >> 5;
    const size_t zo = (size_t)blockIdx.z * K * N;
    const int k0 = blockIdx.x * 32, n0 = blockIdx.y * 32;
#pragma unroll
    for (int p = 0; p < 4; ++p)
        tb[ty + 8 * p][tx] = W[zo + (size_t)(k0 + ty + 8 * p) * N + n0 + tx];
    __syncthreads();
#pragma unroll
    for (int p = 0; p < 4; ++p)
        Wt[zo + (size_t)(n0 + ty + 8 * p) * K + k0 + tx] = f2bf(tb[tx][ty + 8 * p]);
}

// ---------------------------------------------------------------- embed (4 rows/block)
__global__ __launch_bounds__(256) void embed_kernel(
    const float* __restrict__ obs, const int* __restrict__ act,
    const float* __restrict__ rew, const int* __restrict__ sobs,
    const float* __restrict__ W_obs, const float* __restrict__ b_obs,
    const float* __restrict__ E_act, const float* __restrict__ W_rew,
    const float* __restrict__ b_rew, const float* __restrict__ E_time,
    float* __restrict__ x) {
    __shared__ float ob[4][64];
    const int tid = threadIdx.x, lane = tid & 63, w = tid >> 6;
    const int row = blockIdx.x * 4 + w;
    const int b = row >> 9, t = row & 511;
    ob[w][lane] = obs[(size_t)row * 64 + lane];
    const int a = act[row];
    const float r = rew[row];
    const int ti = sobs[b] + t;
#pragma unroll
    for (int c = 0; c < 8; ++c) {
        const int d = lane + 64 * c;
        float acc = b_obs[d] + b_rew[d] + E_act[(size_t)a * D_ + d]
                  + r * W_rew[d] + E_time[(size_t)ti * D_ + d];
#pragma unroll 16
        for (int k = 0; k < 64; ++k) acc = fmaf(ob[w][k], W_obs[k * D_ + d], acc);
        x[(size_t)row * D_ + d] = acc;
    }
}

// ---------------------------------------------------------------- LN -> bf16 (4 rows/block)
__global__ __launch_bounds__(256) void ln_bf16_kernel(
    const float* __restrict__ x, const float* __restrict__ s,
    const float* __restrict__ b, ushort* __restrict__ o) {
    const int tid = threadIdx.x, lane = tid & 63, w = tid >> 6;
    const int row = blockIdx.x * 4 + w;
    const float4* p = (const float4*)(x + (size_t)row * D_);
    float4 a = p[lane], c = p[lane + 64];
    float sm = a.x + a.y + a.z + a.w + c.x + c.y + c.z + c.w;
    float sq = a.x*a.x + a.y*a.y + a.z*a.z + a.w*a.w
             + c.x*c.x + c.y*c.y + c.z*c.z + c.w*c.w;
    sm = wave_sum(sm);
    sq = wave_sum(sq);
    const float mean = sm * (1.0f / 512.0f);
    const float var = sq * (1.0f / 512.0f) - mean * mean;
    const float ri = rsqrtf(var + 1e-6f);
    const float4* s4 = (const float4*)s;
    const float4* b4 = (const float4*)b;
    float4 s1 = s4[lane], b1 = b4[lane];
    ushort4 o1 = { f2bf((a.x - mean) * ri * s1.x + b1.x),
                   f2bf((a.y - mean) * ri * s1.y + b1.y),
                   f2bf((a.z - mean) * ri * s1.z + b1.z),
                   f2bf((a.w - mean) * ri * s1.w + b1.w) };
    *(ushort4*)(o + (size_t)row * D_ + lane * 4) = o1;
    float4 s2 = s4[lane + 64], b2 = b4[lane + 64];
    ushort4 o2 = { f2bf((c.x - mean) * ri * s2.x + b2.x),
                   f2bf((c.y - mean) * ri * s2.y + b2.y),
                   f2bf((c.z - mean) * ri * s2.z + b2.z),
                   f2bf((c.w - mean) * ri * s2.w + b2.w) };
    *(ushort4*)(o + (size_t)row * D_ + (lane + 64) * 4) = o2;
}

// ---------------------------------------------------------------- MFMA GEMM 128x128, BK=64
// C = op(A[M,K]bf16 @ Wt[N,K]bf16^T + bias); RES: f32 +=, else bf16 store.
template <bool GELU, bool RES>
__global__ __launch_bounds__(256) void gemm_bf16(
    const ushort* __restrict__ A, int lda,
    const ushort* __restrict__ Wt,
    const float* __restrict__ bias,
    float* __restrict__ Cf, ushort* __restrict__ Cb, int ldc,
    int K) {
    __shared__ ushort As[128 * 64];
    __shared__ ushort Bs[128 * 64];
    const int tid = threadIdx.x, lane = tid & 63, wid = tid >> 6;
    const int wr = wid >> 1, wc = wid & 1;
    const int lr = lane & 15, lg = lane >> 4;
    const int row0 = blockIdx.y * 128, col0 = blockIdx.x * 128;

    f32x4 zero = {0.f, 0.f, 0.f, 0.f};
    f32x4 acc[4][4];
#pragma unroll
    for (int i = 0; i < 4; ++i)
#pragma unroll
        for (int j = 0; j < 4; ++j) acc[i][j] = zero;

    const int smb = tid >> 3, sk = (tid & 7) * 8;       // staging: 16B per thread per p
    const ushort* Ap = A + (size_t)(row0 + smb) * lda + sk;
    const ushort* Bp = Wt + (size_t)(col0 + smb) * K + sk;
    const int soff = smb * 128 + ((sk * 2) ^ ((smb & 7) << 4));

    short8 ra[4], rb[4];
#pragma unroll
    for (int p = 0; p < 4; ++p) {
        ra[p] = *(const short8*)(Ap + (size_t)(32 * p) * lda);
        rb[p] = *(const short8*)(Bp + (size_t)(32 * p) * K);
    }

    for (int k0 = 0;;) {
        __syncthreads();
#pragma unroll
        for (int p = 0; p < 4; ++p) {
            *(short8*)((char*)As + soff + p * 4096) = ra[p];
            *(short8*)((char*)Bs + soff + p * 4096) = rb[p];
        }
        __syncthreads();
        k0 += 64;
        if (k0 < K) {
#pragma unroll
            for (int p = 0; p < 4; ++p) {
                ra[p] = *(const short8*)(Ap + (size_t)(32 * p) * lda + k0);
                rb[p] = *(const short8*)(Bp + (size_t)(32 * p) * K + k0);
            }
        }
#pragma unroll
        for (int k2 = 0; k2 < 2; ++k2) {
            short8 af[4], bf[4];
#pragma unroll
            for (int i = 0; i < 4; ++i) {
                const int arow = 64 * wr + 16 * i + lr;
                af[i] = *(const short8*)((char*)As + sw(arow, k2 * 64 + lg * 16));
            }
#pragma unroll
            for (int j = 0; j < 4; ++j) {
                const int brow = 64 * wc + 16 * j + lr;
                bf[j] = *(const short8*)((char*)Bs + sw(brow, k2 * 64 + lg * 16));
            }
#pragma unroll
            for (int i = 0; i < 4; ++i)
#pragma unroll
                for (int j = 0; j < 4; ++j) acc[i][j] = MFMA16(af[i], bf[j], acc[i][j]);
        }
        if (k0 >= K) break;
    }

#pragma unroll
    for (int j = 0; j < 4; ++j) {
        const int col = col0 + 64 * wc + 16 * j + lr;
        const float bj = bias[col];
#pragma unroll
        for (int i = 0; i < 4; ++i) {
            const int rbase = row0 + 64 * wr + 16 * i + lg * 4;
#pragma unroll
            for (int r = 0; r < 4; ++r) {
                float v = acc[i][j][r] + bj;
                if (GELU) v = gelu_tanh(v);
                if (RES) {
                    float* p = Cf + (size_t)(rbase + r) * ldc + col;
                    *p = *p + v;
                } else {
                    Cb[(size_t)(rbase + r) * ldc + col] = f2bf(v);
                }
            }
        }
    }
}

// ---------------------------------------------------------------- MFMA linear attention
// per (b,h): 8 tiles of 64: out = tril(QK^T)V + Q*S_run; S_run += K^T V.
// S kept f32 in regs as St[e][d]; out written bf16 over dead q-slice.
__global__ __launch_bounds__(256) void attn_bf16(
    ushort* __restrict__ qkv, const float* __restrict__ sin_,
    float* __restrict__ sout, int layer, int b0) {
    __shared__ ushort Qs[4096], Ks[4096], Kt[4096], Vt[4096], Ps[4096], Stb[4096];
    const int tid = threadIdx.x, lane = tid & 63, w = tid >> 6;
    const int lr = lane & 15, lg = lane >> 4;
    const int bh = blockIdx.x, bl = bh >> 3, h = bh & 7;
    const size_t soff = (((size_t)(b0 + bl) * L_ + layer) * H_ + h) * 4096;

    f32x4 zero = {0.f, 0.f, 0.f, 0.f};
    f32x4 stacc[4];
#pragma unroll
    for (int n = 0; n < 4; ++n)
#pragma unroll
        for (int r = 0; r < 4; ++r)
            stacc[n][r] = sin_[soff + (size_t)(16 * n + lr) * 64 + 16 * w + lg * 4 + r];

    const int st = tid >> 3, sd8 = (tid & 7) * 8;

    for (int tile = 0; tile < 8; ++tile) {
        const int t0 = tile * 64;
#pragma unroll
        for (int p = 0; p < 2; ++p) {
            const int t = st + 32 * p;
            const ushort* g = qkv + (size_t)(bl * T_ + t0 + t) * 1536 + h * 64;
            short8 q8 = *(const short8*)(g + sd8);
            short8 k8 = *(const short8*)(g + 512 + sd8);
            short8 v8 = *(const short8*)(g + 1024 + sd8);
            *(short8*)((char*)Qs + sw(t, sd8 * 2)) = q8;
            *(short8*)((char*)Ks + sw(t, sd8 * 2)) = k8;
#pragma unroll
            for (int j = 0; j < 8; ++j) {
                *(ushort*)((char*)Kt + sw(sd8 + j, t * 2)) = (ushort)k8[j];
                *(ushort*)((char*)Vt + sw(sd8 + j, t * 2)) = (ushort)v8[j];
            }
        }
#pragma unroll
        for (int n = 0; n < 4; ++n)
#pragma unroll
            for (int r = 0; r < 4; ++r)
                *(ushort*)((char*)Stb + sw(16 * w + lg * 4 + r, (16 * n + lr) * 2)) =
                    f2bf(stacc[n][r]);
        __syncthreads();

        short8 aq[2];
#pragma unroll
        for (int k2 = 0; k2 < 2; ++k2)
            aq[k2] = *(const short8*)((char*)Qs + sw(16 * w + lr, k2 * 64 + lg * 16));

        f32x4 pacc[4], oacc[4];
#pragma unroll
        for (int n = 0; n < 4; ++n) { pacc[n] = zero; oacc[n] = zero; }
#pragma unroll
        for (int k2 = 0; k2 < 2; ++k2)
#pragma unroll
            for (int n = 0; n < 4; ++n) {
                short8 bk = *(const short8*)((char*)Ks + sw(16 * n + lr, k2 * 64 + lg * 16));
                pacc[n] = MFMA16(aq[k2], bk, pacc[n]);
            }
#pragma unroll
        for (int k2 = 0; k2 < 2; ++k2)
#pragma unroll
            for (int n = 0; n < 4; ++n) {
                short8 bs = *(const short8*)((char*)Stb + sw(16 * n + lr, k2 * 64 + lg * 16));
                oacc[n] = MFMA16(aq[k2], bs, oacc[n]);
            }
        // causal mask within tile; P -> bf16 LDS
#pragma unroll
        for (int n = 0; n < 4; ++n)
#pragma unroll
            for (int r = 0; r < 4; ++r) {
                const int t = 16 * w + lg * 4 + r, s = 16 * n + lr;
                *(ushort*)((char*)Ps + sw(t, s * 2)) =
                    (s <= t) ? f2bf(pacc[n][r]) : (ushort)0;
            }
        short8 ap[2], av[2];
#pragma unroll
        for (int k2 = 0; k2 < 2; ++k2) {
            ap[k2] = *(const short8*)((char*)Ps + sw(16 * w + lr, k2 * 64 + lg * 16));
            av[k2] = *(const short8*)((char*)Vt + sw(16 * w + lr, k2 * 64 + lg * 16));
        }
#pragma unroll
        for (int k2 = 0; k2 < 2; ++k2)
#pragma unroll
            for (int n = 0; n < 4; ++n) {
                short8 bv = *(const short8*)((char*)Vt + sw(16 * n + lr, k2 * 64 + lg * 16));
                oacc[n] = MFMA16(ap[k2], bv, oacc[n]);
            }
#pragma unroll
        for (int k2 = 0; k2 < 2; ++k2)
#pragma unroll
            for (int n = 0; n < 4; ++n) {
                short8 bkt = *(const short8*)((char*)Kt + sw(16 * n + lr, k2 * 64 + lg * 16));
                stacc[n] = MFMA16(av[k2], bkt, stacc[n]);
            }
#pragma unroll
        for (int n = 0; n < 4; ++n)
#pragma unroll
            for (int r = 0; r < 4; ++r) {
                const int t = 16 * w + lg * 4 + r, e = 16 * n + lr;
                qkv[(size_t)(bl * T_ + t0 + t) * 1536 + h * 64 + e] = f2bf(oacc[n][r]);
            }
        __syncthreads();
    }
#pragma unroll
    for (int n = 0; n < 4; ++n)
#pragma unroll
        for (int r = 0; r < 4; ++r)
            sout[soff + (size_t)(16 * n + lr) * 64 + 16 * w + lg * 4 + r] = stacc[n][r];
}

// ---------------------------------------------------------------- final LN + heads (4 rows/block)
__global__ __launch_bounds__(256) void head_kernel(
    const float* __restrict__ x, const float* __restrict__ lnf_s,
    const float* __restrict__ lnf_b, const float* __restrict__ W_actor,
    const float* __restrict__ b_actor, const float* __restrict__ W_critic,
    const float* __restrict__ b_critic, float* __restrict__ logits,
    float* __restrict__ val) {
    __shared__ float nb[4][512];
    const int tid = threadIdx.x, lane = tid & 63, w = tid >> 6;
    const int row = blockIdx.x * 4 + w;
    const float4* p = (const float4*)(x + (size_t)row * D_);
    float4 a = p[lane], c = p[lane + 64];
    float sm = a.x + a.y + a.z + a.w + c.x + c.y + c.z + c.w;
    float sq = a.x*a.x + a.y*a.y + a.z*a.z + a.w*a.w
             + c.x*c.x + c.y*c.y + c.z*c.z + c.w*c.w;
    sm = wave_sum(sm);
    sq = wave_sum(sq);
    const float mean = sm * (1.0f / 512.0f);
    const float var = sq * (1.0f / 512.0f) - mean * mean;
    const float ri = rsqrtf(var + 1e-6f);
    const float4* s4 = (const float4*)lnf_s;
    const float4* b4 = (const float4*)lnf_b;
    float4 s1 = s4[lane], b1 = b4[lane];
    float4 s2 = s4[lane + 64], b2 = b4[lane + 64];
    float4 n1 = { (a.x - mean) * ri * s1.x + b1.x, (a.y - mean) * ri * s1.y + b1.y,
                  (a.z - mean) * ri * s1.z + b1.z, (a.w - mean) * ri * s1.w + b1.w };
    float4 n2 = { (c.x - mean) * ri * s2.x + b2.x, (c.y - mean) * ri * s2.y + b2.y,
                  (c.z - mean) * ri * s2.z + b2.z, (c.w - mean) * ri * s2.w + b2.w };
    *(float4*)&nb[w][lane * 4] = n1;
    *(float4*)&nb[w][(lane + 64) * 4] = n2;

    float pj[16];
#pragma unroll
    for (int j = 0; j < 16; ++j) pj[j] = 0.0f;
    float pv = 0.0f;
#pragma unroll
    for (int it = 0; it < 8; ++it) {
        const int d = lane + 64 * it;
        const float nv = nb[w][d];
        const float4* wa = (const float4*)(W_actor + d * NACT);
        float4 w0 = wa[0], w1 = wa[1], w2 = wa[2], w3 = wa[3];
        pj[0] = fmaf(nv, w0.x, pj[0]);  pj[1] = fmaf(nv, w0.y, pj[1]);
        pj[2] = fmaf(nv, w0.z, pj[2]);  pj[3] = fmaf(nv, w0.w, pj[3]);
        pj[4] = fmaf(nv, w1.x, pj[4]);  pj[5] = fmaf(nv, w1.y, pj[5]);
        pj[6] = fmaf(nv, w1.z, pj[6]);  pj[7] = fmaf(nv, w1.w, pj[7]);
        pj[8] = fmaf(nv, w2.x, pj[8]);  pj[9] = fmaf(nv, w2.y, pj[9]);
        pj[10] = fmaf(nv, w2.z, pj[10]); pj[11] = fmaf(nv, w2.w, pj[11]);
        pj[12] = fmaf(nv, w3.x, pj[12]); pj[13] = fmaf(nv, w3.y, pj[13]);
        pj[14] = fmaf(nv, w3.z, pj[14]); pj[15] = fmaf(nv, w3.w, pj[15]);
        pv = fmaf(nv, W_critic[d], pv);
    }
#pragma unroll
    for (int j = 0; j < 16; ++j) pj[j] = wave_sum(pj[j]);
    pv = wave_sum(pv);
    if (lane == 0) {
#pragma unroll
        for (int j = 0; j < 16; ++j) logits[(size_t)row * NACT + j] = pj[j] + b_actor[j];
        val[row] = pv + b_critic[0];
    }
}

__global__ void sobs_kernel(const int* __restrict__ sobs, float* __restrict__ out) {
    const int i = threadIdx.x;
    if (i < B_) out[i] = (float)(sobs[i] + T_);
}

// ---------------------------------------------------------------- launch
extern "C" void kernel_launch(void* const* d_in, const int* in_sizes, int n_in,
                              void* d_out, int out_size, void* d_ws, size_t ws_size,
                              hipStream_t stream) {
    const float* obs     = (const float*)d_in[0];
    const int*   act_p   = (const int*)d_in[1];
    const float* rew_p   = (const float*)d_in[2];
    const int*   sobs    = (const int*)d_in[3];
    const float* sblk    = (const float*)d_in[4];
    const float* W_obs   = (const float*)d_in[5];
    const float* b_obs   = (const float*)d_in[6];
    const float* E_act   = (const float*)d_in[7];
    const float* W_rew   = (const float*)d_in[8];
    const float* b_rew   = (const float*)d_in[9];
    const float* E_time  = (const float*)d_in[10];
    const float* ln1_s   = (const float*)d_in[11];
    const float* ln1_b   = (const float*)d_in[12];
    const float* Wqkv    = (const float*)d_in[13];
    const float* bqkv    = (const float*)d_in[14];
    const float* Wout    = (const float*)d_in[15];
    const float* bout    = (const float*)d_in[16];
    const float* ln2_s   = (const float*)d_in[17];
    const float* ln2_b   = (const float*)d_in[18];
    const float* W1      = (const float*)d_in[19];
    const float* b1      = (const float*)d_in[20];
    const float* W2      = (const float*)d_in[21];
    const float* b2      = (const float*)d_in[22];
    const float* lnf_s   = (const float*)d_in[23];
    const float* lnf_b   = (const float*)d_in[24];
    const float* W_actor = (const float*)d_in[25];
    const float* b_actor = (const float*)d_in[26];
    const float* W_crit  = (const float*)d_in[27];
    const float* b_crit  = (const float*)d_in[28];

    float* out        = (float*)d_out;
    float* out_blocks = out;
    float* out_sobs   = out + (size_t)B_ * L_ * H_ * 64 * 64;
    float* out_logits = out_sobs + B_;
    float* out_val    = out_logits + (size_t)ROWS * NACT;

    float*  x   = (float*)d_ws;                         // ROWS*512 f32   (64 MB)
    ushort* h   = (ushort*)(x + (size_t)ROWS * D_);     // CH_ROWS*512    (8 MB)
    ushort* big = h + (size_t)CH_ROWS * D_;             // CH_ROWS*2048   (32 MB)
    ushort* wq  = big + (size_t)CH_ROWS * DFF;          // 4*512*1536
    ushort* wo  = wq + (size_t)L_ * D_ * 3 * D_;        // 4*512*512
    ushort* w1t = wo + (size_t)L_ * D_ * D_;            // 4*512*2048
    ushort* w2t = w1t + (size_t)L_ * D_ * DFF;          // 4*2048*512
    const size_t need = (size_t)ROWS * D_ * 4 + (size_t)CH_ROWS * D_ * 2
                      + (size_t)CH_ROWS * DFF * 2
                      + ((size_t)L_ * (D_ * 3 * D_ + D_ * D_ + 2 * D_ * DFF)) * 2;
    if (ws_size < need) return;  // fail soft

    wtrans<<<dim3(16, 48, L_), 256, 0, stream>>>(Wqkv, wq, D_, 3 * D_);
    wtrans<<<dim3(16, 16, L_), 256, 0, stream>>>(Wout, wo, D_, D_);
    wtrans<<<dim3(16, 64, L_), 256, 0, stream>>>(W1, w1t, D_, DFF);
    wtrans<<<dim3(64, 16, L_), 256, 0, stream>>>(W2, w2t, DFF, D_);

    embed_kernel<<<ROWS / 4, 256, 0, stream>>>(obs, act_p, rew_p, sobs, W_obs, b_obs,
                                               E_act, W_rew, b_rew, E_time, x);
    for (int l = 0; l < L_; ++l) {
        for (int rc = 0; rc < RC_; ++rc) {
            const size_t ro = (size_t)rc * CH_ROWS;
            ln_bf16_kernel<<<CH_ROWS / 4, 256, 0, stream>>>(
                x + ro * D_, ln1_s + l * D_, ln1_b + l * D_, h);
            gemm_bf16<false, false><<<dim3(12, 64), 256, 0, stream>>>(
                h, D_, wq + (size_t)l * D_ * 3 * D_, bqkv + l * 3 * D_,
                nullptr, big, 3 * D_, D_);
            attn_bf16<<<CH_B * H_, 256, 0, stream>>>(big, sblk, out_blocks, l, rc * CH_B);
            gemm_bf16<false, true><<<dim3(4, 64), 256, 0, stream>>>(
                big, 3 * D_, wo + (size_t)l * D_ * D_, bout + l * D_,
                x + ro * D_, nullptr, D_, D_);
            ln_bf16_kernel<<<CH_ROWS / 4, 256, 0, stream>>>(
                x + ro * D_, ln2_s + l * D_, ln2_b + l * D_, h);
            gemm_bf16<true, false><<<dim3(16, 64), 256, 0, stream>>>(
                h, D_, w1t + (size_t)l * D_ * DFF, b1 + l * DFF,
                nullptr, big, DFF, D_);
            gemm_bf16<false, true><<<dim3(4, 64), 256, 0, stream>>>(
                big, DFF, w2t + (size_t)l * DFF * D_, b2 + l * D_,
                x + ro * D_, nullptr, D_, DFF);
        }
    }
    head_kernel<<<ROWS / 4, 256, 0, stream>>>(x, lnf_s, lnf_b, W_actor, b_actor,
                                              W_crit, b_crit, out_logits, out_val);
    sobs_kernel<<<1, 64, 0, stream>>>(sobs, out_sobs);
}